// Round 2
// baseline (316.658 us; speedup 1.0000x reference)
//
#include <hip/hip_runtime.h>
#include <math.h>

#define T_STEPS 256
#define BATCH   2048
#define HID     10

// fast activations (v_exp_f32 / v_rcp_f32 / v_log_f32 paths)
__device__ __forceinline__ float ftanh(float x){ return 1.f - 2.f/(1.f + __expf(2.f*x)); }
__device__ __forceinline__ float fsigm(float x){ return 1.f/(1.f + __expf(-x)); }
__device__ __forceinline__ float frcp (float x){ return __builtin_amdgcn_rcpf(x); }

// DPP row rotate-right by K within each 16-lane row: result[lane j] = src[(j-K)&15]
// (row_shr:1 gives lane N <- N-1 per the classic DPP scan idiom; ror wraps.)
template<int K> __device__ __forceinline__ float rotk(float x){
  return __int_as_float(__builtin_amdgcn_update_dpp(
      0, __float_as_int(x), 0x120 + K, 0xF, 0xF, false));
}

#define ROT16(r, v) do{ float _v=(v); r[0]=_v; \
  r[1]=rotk<1>(_v);  r[2]=rotk<2>(_v);  r[3]=rotk<3>(_v);  r[4]=rotk<4>(_v);  \
  r[5]=rotk<5>(_v);  r[6]=rotk<6>(_v);  r[7]=rotk<7>(_v);  r[8]=rotk<8>(_v);  \
  r[9]=rotk<9>(_v);  r[10]=rotk<10>(_v);r[11]=rotk<11>(_v);r[12]=rotk<12>(_v);\
  r[13]=rotk<13>(_v);r[14]=rotk<14>(_v);r[15]=rotk<15>(_v); }while(0)

// 16-term dot with 4-way split accumulators (short dep chains)
__device__ __forceinline__ float dot16(const float* r, const float* w, float bias){
  float a0 = fmaf(r[0], w[0], bias);
  float a1 = r[1]*w[1];
  float a2 = r[2]*w[2];
  float a3 = r[3]*w[3];
  #pragma unroll
  for (int k=4;k<16;k+=4){
    a0 = fmaf(r[k  ], w[k  ], a0);
    a1 = fmaf(r[k+1], w[k+1], a1);
    a2 = fmaf(r[k+2], w[k+2], a2);
    a3 = fmaf(r[k+3], w[k+3], a3);
  }
  return (a0+a1)+(a2+a3);
}

// load weight column `col` of an NROW x NCOL matrix, pre-rotated for rotk order:
// dst[k] = W[(j-k)&15][col] if that row exists (and colok), else 0
template<int NROW, int NCOL>
__device__ __forceinline__ void loadrot(float* dst, const float* W, int j, int col, bool colok){
  int colc = colok ? col : 0;
  #pragma unroll
  for (int k=0;k<16;k++){
    int i = (j - k) & 15;
    bool v = colok && (i < NROW);
    int ic = v ? i : 0;
    float w = W[ic*NCOL + colc];
    dst[k] = v ? w : 0.f;
  }
}

__device__ __forceinline__ float bload(const float* p, int idx, bool ok){
  float t = p[ok ? idx : 0];
  return ok ? t : 0.f;
}

// final 16-lane butterfly (used ONCE at kernel end)
template<int X> __device__ __forceinline__ float xor16(float x){
  return __int_as_float(__builtin_amdgcn_ds_swizzle(__float_as_int(x), (X<<10)|0x1f));
}

struct P34 { const float* p[34]; float* out; };

// one chain per 16 lanes; lane j owns state element j (lanes 10..15 zero-weighted)
__global__ __launch_bounds__(256, 1) void dvbf_fwd(P34 prm)
{
  const int tid = threadIdx.x;
  const int j   = tid & 15;
  const int grp = tid >> 4;
  const int b   = blockIdx.x * 16 + grp;
  const bool act = (j < HID);
  const int  jl  = act ? j : 0;

  const float* __restrict__ seq   = prm.p[0];
  const float* __restrict__ noise = prm.p[1];
  float* __restrict__ out = prm.out;

  // ---------------- pre-rotated per-lane weights (all VGPR-resident) ----------------
  // first_inference (dies after prologue)
  float w_fi0, w_fi1, b_fi_in, w_fi_h[16], b_fi_h, w_fi_mu[16], b_fi_mu, w_fi_sg[16], b_fi_sg;
  w_fi0 = bload(prm.p[2],       jl, act);     // fi_in_W[0][j]
  w_fi1 = bload(prm.p[2], 10 +  jl, act);     // fi_in_W[1][j]
  b_fi_in = bload(prm.p[3], jl, act);
  loadrot<10,10>(w_fi_h,  prm.p[4], j, j, act);  b_fi_h  = bload(prm.p[5], jl, act);
  loadrot<10,10>(w_fi_mu, prm.p[6], j, j, act);  b_fi_mu = bload(prm.p[7], jl, act);
  loadrot<10,10>(w_fi_sg, prm.p[8], j, j, act);  b_fi_sg = bload(prm.p[9], jl, act);

  // inference
  float w_ii0, w_ii1, b_in_in;
  float w_in_j_e[16], w_in_j_z[16], b_in_j, w_in_h[16], b_in_h;
  float w_in_mu[16], b_in_mu, w_in_sg[16], b_in_sg;
  w_ii0 = bload(prm.p[10],      jl, act);
  w_ii1 = bload(prm.p[10], 10 + jl, act);
  b_in_in = bload(prm.p[11], jl, act);
  loadrot<10,10>(w_in_j_e, prm.p[12],        j, j, act);  // rows 0..9  (e part)
  loadrot<10,10>(w_in_j_z, prm.p[12] + 100,  j, j, act);  // rows 10..19 (z part)
  b_in_j  = bload(prm.p[13], jl, act);
  loadrot<10,10>(w_in_h,  prm.p[14], j, j, act);  b_in_h  = bload(prm.p[15], jl, act);
  loadrot<10,10>(w_in_mu, prm.p[16], j, j, act);  b_in_mu = bload(prm.p[17], jl, act);
  loadrot<10,10>(w_in_sg, prm.p[18], j, j, act);  b_in_sg = bload(prm.p[19], jl, act);

  // transition
  float w_tr_h[16], b_tr_h, w_tr_mu[16], b_tr_mu, w_tr_sg[16], b_tr_sg;
  loadrot<10,10>(w_tr_h,  prm.p[20], j, j, act);  b_tr_h  = bload(prm.p[21], jl, act);
  loadrot<10,10>(w_tr_mu, prm.p[22], j, j, act);  b_tr_mu = bload(prm.p[23], jl, act);
  loadrot<10,10>(w_tr_sg, prm.p[24], j, j, act);  b_tr_sg = bload(prm.p[25], jl, act);

  // generator (lanes 0,1 own output dims 0,1 of both mu and sg)
  float w_g1[16], b_g1, w_g2[16], b_g2;
  float w_go_mu[16], b_go_mu, w_go_sg[16], b_go_sg;
  loadrot<10,10>(w_g1, prm.p[26], j, j, act);  b_g1 = bload(prm.p[27], jl, act);
  loadrot<10,10>(w_g2, prm.p[28], j, j, act);  b_g2 = bload(prm.p[29], jl, act);
  const bool isd = (j < 2);
  loadrot<10,2>(w_go_mu, prm.p[30], j, j, isd);  b_go_mu = bload(prm.p[31], j, isd);
  loadrot<10,2>(w_go_sg, prm.p[32], j, j, isd);  b_go_sg = bload(prm.p[33], j, isd);

  // ---------------- recurrence ----------------
  float lacc = 0.f;          // per-lane loss partial
  float rz[16];              // rotated latent state (reused by generator, transition, inference)
  int sOff = b*2;
  int nOff = b*HID + jl;
  int gOff = b*2;

  auto generator = [&](float x0, float x1, int go){
    float g1 = fmaxf(dot16(rz,  w_g1, b_g1), 0.f);
    float rg1[16]; ROT16(rg1, g1);
    float g2 = fmaxf(dot16(rg1, w_g2, b_g2), 0.f);
    float rg2[16]; ROT16(rg2, g2);
    float m = fsigm(dot16(rg2, w_go_mu, b_go_mu));
    float s = fsigm(dot16(rg2, w_go_sg, b_go_sg));
    if (j < 2){
      out[go + j] = m;
      float xd = (j==0) ? x0 : x1;
      float dd = xd - m;
      lacc -= 0.5f*(__logf(s) + dd*dd*frcp(s));
    }
  };

  { // t = 0: first_inference vs unit prior
    float2 x = *reinterpret_cast<const float2*>(seq + sOff);
    float eps = noise[nOff];
    float h0 = ftanh(fmaf(x.x, w_fi0, fmaf(x.y, w_fi1, b_fi_in)));
    float r0[16]; ROT16(r0, h0);
    float h1 = ftanh(dot16(r0, w_fi_h, b_fi_h));
    float r1[16]; ROT16(r1, h1);
    float mu = ftanh(dot16(r1, w_fi_mu, b_fi_mu));
    float sg = fsigm(dot16(r1, w_fi_sg, b_fi_sg)) + 0.001f;
    if (act) lacc += 0.5f*(sg + mu*mu - __logf(sg));   // KL vs N(0,1), -5 folded at end
    float z = fmaf(sg, eps, mu);
    ROT16(rz, z);
    generator(x.x, x.y, gOff);
  }

  for (int t = 1; t < T_STEPS; ++t){
    sOff += BATCH*2; nOff += BATCH*HID; gOff += BATCH*2;
    float2 x = *reinterpret_cast<const float2*>(seq + sOff);
    float eps = noise[nOff];

    // transition (prior) — independent of inference path, ILP-overlapped
    float th = ftanh(dot16(rz, w_tr_h, b_tr_h));
    float rth[16]; ROT16(rth, th);
    float pr_mu = ftanh(dot16(rth, w_tr_mu, b_tr_mu));
    float pr_sg = ftanh(dot16(rth, w_tr_sg, b_tr_sg));

    // inference (posterior)
    float e = ftanh(fmaf(x.x, w_ii0, fmaf(x.y, w_ii1, b_in_in)));
    float re[16]; ROT16(re, e);
    float hj = ftanh(dot16(re, w_in_j_e, b_in_j) + dot16(rz, w_in_j_z, 0.f));
    float rhj[16]; ROT16(rhj, hj);
    float hi = ftanh(dot16(rhj, w_in_h, b_in_h));
    float rhi[16]; ROT16(rhi, hi);
    float q_mu = ftanh(dot16(rhi, w_in_mu, b_in_mu));
    float q_sg = fsigm(dot16(rhi, w_in_sg, b_in_sg)) + 0.001f;

    // KLD per-lane term (constants folded at end)
    if (act){
      float dmu = pr_mu - q_mu;
      float rp  = frcp(pr_sg);
      lacc += 0.5f*(__logf(pr_sg*frcp(q_sg)) + (q_sg + dmu*dmu)*rp);
    }

    // reparameterized sample -> rotated state
    float z = fmaf(q_sg, eps, q_mu);
    ROT16(rz, z);

    generator(x.x, x.y, gOff);
  }

  // single end-of-kernel reduction of per-lane loss partials
  float s = lacc;
  s += xor16<1>(s); s += xor16<2>(s); s += xor16<4>(s); s += xor16<8>(s);
  if (j == 0){
    const float LOGPI = 1.1447298858494002f;
    // true_loss = S - 5*T - T*logpi ; out = -true_loss/T = -S/T + 5 + logpi
    out[T_STEPS*BATCH*2 + b] = -s*(1.0f/(float)T_STEPS) + 5.0f + LOGPI;
  }
}

extern "C" void kernel_launch(void* const* d_in, const int* in_sizes, int n_in,
                              void* d_out, int out_size, void* d_ws, size_t ws_size,
                              hipStream_t stream) {
  P34 prm;
  for (int i = 0; i < 34; ++i) prm.p[i] = (const float*)d_in[i];
  prm.out = (float*)d_out;
  dim3 grid(BATCH/16), block(256);   // 16 chains/block, 4 waves
  hipLaunchKernelGGL(dvbf_fwd, grid, block, 0, stream, prm);
}

// Round 3
// 300.772 us; speedup vs baseline: 1.0528x; 1.0528x over previous
//
#include <hip/hip_runtime.h>
#include <math.h>

#define T_STEPS 256
#define BATCH   2048
#define HID     10

// ws layout (floats): z | qmu | qsg | kl | ll   == 16,777,216 floats = 64 MiB
#define ZOFF   0
#define QMUOFF (T_STEPS*BATCH*HID)
#define QSGOFF (2*T_STEPS*BATCH*HID)
#define KLOFF  (3*T_STEPS*BATCH*HID)
#define LLOFF  (KLOFF + T_STEPS*BATCH)

__device__ __forceinline__ float ftanh(float x){ return 1.f - 2.f/(1.f + __expf(2.f*x)); }
__device__ __forceinline__ float fsigm(float x){ return 1.f/(1.f + __expf(-x)); }
__device__ __forceinline__ float frcp (float x){ return __builtin_amdgcn_rcpf(x); }

// DPP row rotate-right by K within each 16-lane row: result[lane j] = src[(j-K)&15]
template<int K> __device__ __forceinline__ float rotk(float x){
  return __int_as_float(__builtin_amdgcn_update_dpp(
      0, __float_as_int(x), 0x120 + K, 0xF, 0xF, false));
}
#define ROT16(r, v) do{ float _v=(v); r[0]=_v; \
  r[1]=rotk<1>(_v);  r[2]=rotk<2>(_v);  r[3]=rotk<3>(_v);  r[4]=rotk<4>(_v);  \
  r[5]=rotk<5>(_v);  r[6]=rotk<6>(_v);  r[7]=rotk<7>(_v);  r[8]=rotk<8>(_v);  \
  r[9]=rotk<9>(_v);  r[10]=rotk<10>(_v);r[11]=rotk<11>(_v);r[12]=rotk<12>(_v);\
  r[13]=rotk<13>(_v);r[14]=rotk<14>(_v);r[15]=rotk<15>(_v); }while(0)

__device__ __forceinline__ float dot16(const float* r, const float* w, float bias){
  float a0 = fmaf(r[0], w[0], bias);
  float a1 = r[1]*w[1];
  float a2 = r[2]*w[2];
  float a3 = r[3]*w[3];
  #pragma unroll
  for (int k=4;k<16;k+=4){
    a0 = fmaf(r[k  ], w[k  ], a0);
    a1 = fmaf(r[k+1], w[k+1], a1);
    a2 = fmaf(r[k+2], w[k+2], a2);
    a3 = fmaf(r[k+3], w[k+3], a3);
  }
  return (a0+a1)+(a2+a3);
}

// dst[k] = W[(j-k)&15][col] if valid else 0  (pre-rotated for rotk order)
template<int NROW, int NCOL>
__device__ __forceinline__ void loadrot(float* dst, const float* W, int j, int col, bool colok){
  int colc = colok ? col : 0;
  #pragma unroll
  for (int k=0;k<16;k++){
    int i = (j - k) & 15;
    bool v = colok && (i < NROW);
    int ic = v ? i : 0;
    float w = W[ic*NCOL + colc];
    dst[k] = v ? w : 0.f;
  }
}
__device__ __forceinline__ float bload(const float* p, int idx, bool ok){
  float t = p[ok ? idx : 0];
  return ok ? t : 0.f;
}
template<int X> __device__ __forceinline__ float xor16(float x){
  return __int_as_float(__builtin_amdgcn_ds_swizzle(__float_as_int(x), (X<<10)|0x1f));
}

struct P34 { const float* p[34]; float* ws; float* out; };

// ================= K1: serial inference recurrence (the only sequential part) =================
__global__ __launch_bounds__(64, 1) void k1_recur(P34 prm)
{
  const int tid = threadIdx.x;
  const int j   = tid & 15;
  const int grp = tid >> 4;              // 0..3
  const int b   = blockIdx.x*4 + grp;    // chain id (512 blocks)
  const bool act = (j < HID);
  const int  jl  = act ? j : 0;

  const float* __restrict__ seq   = prm.p[0];
  const float* __restrict__ noise = prm.p[1];
  float* __restrict__ ws = prm.ws;

  // inference weights (live through the loop: 5x16 + in-vec)
  float w_ii0   = bload(prm.p[10],      jl, act);
  float w_ii1   = bload(prm.p[10], 10 + jl, act);
  float b_in_in = bload(prm.p[11], jl, act);
  float w_in_j_e[16], w_in_j_z[16], w_in_h[16], w_in_mu[16], w_in_sg[16];
  loadrot<10,10>(w_in_j_e, prm.p[12],       j, j, act);
  loadrot<10,10>(w_in_j_z, prm.p[12] + 100, j, j, act);
  float b_in_j  = bload(prm.p[13], jl, act);
  loadrot<10,10>(w_in_h,  prm.p[14], j, j, act);  float b_in_h  = bload(prm.p[15], jl, act);
  loadrot<10,10>(w_in_mu, prm.p[16], j, j, act);  float b_in_mu = bload(prm.p[17], jl, act);
  loadrot<10,10>(w_in_sg, prm.p[18], j, j, act);  float b_in_sg = bload(prm.p[19], jl, act);

  float rz[16];
  int sOff = b*2, nOff = b*HID + jl;
  int zW = b*HID + jl;

  { // t = 0: first_inference (weights die after this scope) + KL vs N(0,1)
    float w0 = bload(prm.p[2],      jl, act);
    float w1 = bload(prm.p[2], 10 + jl, act);
    float bb = bload(prm.p[3], jl, act);
    float w_h[16], w_mu[16], w_sg[16];
    loadrot<10,10>(w_h,  prm.p[4], j, j, act);  float b_h  = bload(prm.p[5], jl, act);
    loadrot<10,10>(w_mu, prm.p[6], j, j, act);  float b_mu = bload(prm.p[7], jl, act);
    loadrot<10,10>(w_sg, prm.p[8], j, j, act);  float b_sg = bload(prm.p[9], jl, act);
    float2 x = *reinterpret_cast<const float2*>(seq + sOff);
    float eps = noise[nOff];
    float h0 = ftanh(fmaf(x.x, w0, fmaf(x.y, w1, bb)));
    float r0[16]; ROT16(r0, h0);
    float h1 = ftanh(dot16(r0, w_h, b_h));
    float r1[16]; ROT16(r1, h1);
    float mu = ftanh(dot16(r1, w_mu, b_mu));
    float sg = fsigm(dot16(r1, w_sg, b_sg)) + 0.001f;
    float term = act ? (sg + mu*mu - __logf(sg)) : 0.f;
    term += xor16<1>(term); term += xor16<2>(term); term += xor16<4>(term); term += xor16<8>(term);
    if (j == 0) ws[KLOFF + b] = 0.5f*term;            // kl_half(t=0)
    float z = fmaf(sg, eps, mu);
    if (act){
      ws[ZOFF   + zW] = z;
      ws[QMUOFF + zW] = mu;
      ws[QSGOFF + zW] = sg;
    }
    ROT16(rz, z);
  }

  // prefetch t=1
  float2 xn  = *reinterpret_cast<const float2*>(seq + sOff + BATCH*2);
  float epsn = noise[nOff + BATCH*HID];

  for (int t = 1; t < T_STEPS; ++t){
    float2 x = xn; float eps = epsn;
    sOff += BATCH*2; nOff += BATCH*HID; zW += BATCH*HID;
    int pre = (t < T_STEPS-1) ? 1 : 0;
    xn   = *reinterpret_cast<const float2*>(seq + sOff + pre*BATCH*2);
    epsn = noise[nOff + pre*BATCH*HID];

    float e = ftanh(fmaf(x.x, w_ii0, fmaf(x.y, w_ii1, b_in_in)));
    float re[16]; ROT16(re, e);
    float hj = ftanh(dot16(re, w_in_j_e, b_in_j) + dot16(rz, w_in_j_z, 0.f));
    float rhj[16]; ROT16(rhj, hj);
    float hi = ftanh(dot16(rhj, w_in_h, b_in_h));
    float rhi[16]; ROT16(rhi, hi);
    float q_mu = ftanh(dot16(rhi, w_in_mu, b_in_mu));
    float q_sg = fsigm(dot16(rhi, w_in_sg, b_in_sg)) + 0.001f;
    float z = fmaf(q_sg, eps, q_mu);
    if (act){
      ws[ZOFF   + zW] = z;
      ws[QMUOFF + zW] = q_mu;
      ws[QSGOFF + zW] = q_sg;
    }
    ROT16(rz, z);
  }
}

// ================= K2a: transition + KLD for t = 1..255 (parallel over (t,b)) =================
__global__ __launch_bounds__(256, 1) void k2_kl(P34 prm)
{
  const int tid = threadIdx.x;
  const int j   = tid & 15;
  const int gg  = blockIdx.x*16 + (tid >> 4);   // 16384 groups
  const bool act = (j < HID);
  const int  jl  = act ? j : 0;
  float* __restrict__ ws = prm.ws;

  float w_h[16], w_mu[16], w_sg[16];
  loadrot<10,10>(w_h,  prm.p[20], j, j, act);  float b_h  = bload(prm.p[21], jl, act);
  loadrot<10,10>(w_mu, prm.p[22], j, j, act);  float b_mu = bload(prm.p[23], jl, act);
  loadrot<10,10>(w_sg, prm.p[24], j, j, act);  float b_sg = bload(prm.p[25], jl, act);

  for (int it = 0; it < 32; ++it){
    int i = it*16384 + gg;                      // item over t=1..255, b
    if (i >= (T_STEPS-1)*BATCH) break;
    int t = 1 + (i >> 11);
    int b = i & (BATCH-1);
    int zo = ((t-1)*BATCH + b)*HID + jl;
    int qo = (t*BATCH + b)*HID + jl;
    float zp  = act ? ws[ZOFF   + zo] : 0.f;
    float qmu = act ? ws[QMUOFF + qo] : 0.f;
    float qsg = act ? ws[QSGOFF + qo] : 1.f;
    float rzp[16]; ROT16(rzp, zp);
    float th = ftanh(dot16(rzp, w_h, b_h));
    float rth[16]; ROT16(rth, th);
    float prmu = ftanh(dot16(rth, w_mu, b_mu));
    float prsg = ftanh(dot16(rth, w_sg, b_sg));
    float term = 0.f;
    if (act){
      float dmu = prmu - qmu;
      float rp  = frcp(prsg);
      term = __logf(prsg*frcp(qsg)) + (qsg + dmu*dmu)*rp;
    }
    term += xor16<1>(term); term += xor16<2>(term); term += xor16<4>(term); term += xor16<8>(term);
    if (j == 0) ws[KLOFF + t*BATCH + b] = 0.5f*term;
  }
}

// ================= K2b: generator + GLL for t = 0..255 (parallel over (t,b)) =================
__global__ __launch_bounds__(256, 1) void k2_gen(P34 prm)
{
  const int tid = threadIdx.x;
  const int j   = tid & 15;
  const int gg  = blockIdx.x*16 + (tid >> 4);
  const bool act = (j < HID);
  const int  jl  = act ? j : 0;
  float* __restrict__ ws = prm.ws;
  const float* __restrict__ seq = prm.p[0];
  float* __restrict__ out = prm.out;

  float w_g1[16], w_g2[16], w_go_mu[16], w_go_sg[16];
  loadrot<10,10>(w_g1, prm.p[26], j, j, act);  float b_g1 = bload(prm.p[27], jl, act);
  loadrot<10,10>(w_g2, prm.p[28], j, j, act);  float b_g2 = bload(prm.p[29], jl, act);
  const bool isd = (j < 2);
  loadrot<10,2>(w_go_mu, prm.p[30], j, j, isd);  float b_go_mu = bload(prm.p[31], j, isd);
  loadrot<10,2>(w_go_sg, prm.p[32], j, j, isd);  float b_go_sg = bload(prm.p[33], j, isd);

  for (int it = 0; it < 32; ++it){
    int i = it*16384 + gg;                      // exactly 524288 items
    int t = i >> 11;
    int b = i & (BATCH-1);
    int zo = (t*BATCH + b)*HID + jl;
    float zc = act ? ws[ZOFF + zo] : 0.f;
    float rz[16]; ROT16(rz, zc);
    float g1 = fmaxf(dot16(rz, w_g1, b_g1), 0.f);
    float r1[16]; ROT16(r1, g1);
    float g2 = fmaxf(dot16(r1, w_g2, b_g2), 0.f);
    float r2[16]; ROT16(r2, g2);
    float m = fsigm(dot16(r2, w_go_mu, b_go_mu));
    float s = fsigm(dot16(r2, w_go_sg, b_go_sg));
    float ll = 0.f;
    int go = (t*BATCH + b)*2;
    if (isd){
      float xd = seq[go + j];
      out[go + j] = m;
      float dd = xd - m;
      ll = __logf(s) + dd*dd*frcp(s);
    }
    ll += xor16<1>(ll);
    if (j == 0) ws[LLOFF + t*BATCH + b] = -0.5f*ll;
  }
}

// ================= K3: loss reduction over t =================
__global__ __launch_bounds__(256, 1) void k3_loss(P34 prm)
{
  const int b = blockIdx.x*256 + threadIdx.x;   // grid 8 -> 2048
  const float* __restrict__ kl = prm.ws + KLOFF;
  const float* __restrict__ ll = prm.ws + LLOFF;
  float s = 0.f;
  for (int t = 0; t < T_STEPS; ++t)
    s += kl[t*BATCH + b] + ll[t*BATCH + b];
  const float LOGPI = 1.1447298858494002f;
  // true loss[b] = s - T*5 - T*logpi ; out = -loss/T
  prm.out[T_STEPS*BATCH*2 + b] = -s*(1.0f/(float)T_STEPS) + 5.0f + LOGPI;
}

extern "C" void kernel_launch(void* const* d_in, const int* in_sizes, int n_in,
                              void* d_out, int out_size, void* d_ws, size_t ws_size,
                              hipStream_t stream) {
  P34 prm;
  for (int i = 0; i < 34; ++i) prm.p[i] = (const float*)d_in[i];
  prm.ws  = (float*)d_ws;      // needs 64 MiB
  prm.out = (float*)d_out;
  hipLaunchKernelGGL(k1_recur, dim3(512),  dim3(64),  0, stream, prm);
  hipLaunchKernelGGL(k2_kl,    dim3(1024), dim3(256), 0, stream, prm);
  hipLaunchKernelGGL(k2_gen,   dim3(1024), dim3(256), 0, stream, prm);
  hipLaunchKernelGGL(k3_loss,  dim3(8),    dim3(256), 0, stream, prm);
}

// Round 4
// 283.586 us; speedup vs baseline: 1.1166x; 1.0606x over previous
//
#include <hip/hip_runtime.h>
#include <math.h>

#define T_STEPS 256
#define BATCH   2048
#define HID     10

// ws layout (floats): z | qmu | qsg | kl | ll   == 16,777,216 floats = 64 MiB
#define ZOFF   0
#define QMUOFF (T_STEPS*BATCH*HID)
#define QSGOFF (2*T_STEPS*BATCH*HID)
#define KLOFF  (3*T_STEPS*BATCH*HID)
#define LLOFF  (KLOFF + T_STEPS*BATCH)

__device__ __forceinline__ float ftanh(float x){ return 1.f - 2.f/(1.f + __expf(2.f*x)); }
__device__ __forceinline__ float fsigm(float x){ return 1.f/(1.f + __expf(-x)); }
__device__ __forceinline__ float frcp (float x){ return __builtin_amdgcn_rcpf(x); }

// DPP row rotate-right by K within each 16-lane row: result[lane j] = src[(j-K)&15]
template<int K> __device__ __forceinline__ float rotk(float x){
  return __int_as_float(__builtin_amdgcn_update_dpp(
      0, __float_as_int(x), 0x120 + K, 0xF, 0xF, false));
}
#define ROT16(r, v) do{ float _v=(v); r[0]=_v; \
  r[1]=rotk<1>(_v);  r[2]=rotk<2>(_v);  r[3]=rotk<3>(_v);  r[4]=rotk<4>(_v);  \
  r[5]=rotk<5>(_v);  r[6]=rotk<6>(_v);  r[7]=rotk<7>(_v);  r[8]=rotk<8>(_v);  \
  r[9]=rotk<9>(_v);  r[10]=rotk<10>(_v);r[11]=rotk<11>(_v);r[12]=rotk<12>(_v);\
  r[13]=rotk<13>(_v);r[14]=rotk<14>(_v);r[15]=rotk<15>(_v); }while(0)

__device__ __forceinline__ float dot16(const float* r, const float* w, float bias){
  float a0 = fmaf(r[0], w[0], bias);
  float a1 = r[1]*w[1];
  float a2 = r[2]*w[2];
  float a3 = r[3]*w[3];
  #pragma unroll
  for (int k=4;k<16;k+=4){
    a0 = fmaf(r[k  ], w[k  ], a0);
    a1 = fmaf(r[k+1], w[k+1], a1);
    a2 = fmaf(r[k+2], w[k+2], a2);
    a3 = fmaf(r[k+3], w[k+3], a3);
  }
  return (a0+a1)+(a2+a3);
}

// dst[k] = W[(j-k)&15][col] if valid else 0  (pre-rotated for rotk order)
template<int NROW, int NCOL>
__device__ __forceinline__ void loadrot(float* dst, const float* W, int j, int col, bool colok){
  int colc = colok ? col : 0;
  #pragma unroll
  for (int k=0;k<16;k++){
    int i = (j - k) & 15;
    bool v = colok && (i < NROW);
    int ic = v ? i : 0;
    float w = W[ic*NCOL + colc];
    dst[k] = v ? w : 0.f;
  }
}
__device__ __forceinline__ float bload(const float* p, int idx, bool ok){
  float t = p[ok ? idx : 0];
  return ok ? t : 0.f;
}
template<int X> __device__ __forceinline__ float xor16(float x){
  return __int_as_float(__builtin_amdgcn_ds_swizzle(__float_as_int(x), (X<<10)|0x1f));
}

// pin a value into a VGPR (opaque redefinition: compiler can't re-load/remat it)
#define PIN1(x)  asm volatile("" : "+v"(x))
#define PIN16(a) do{ _Pragma("unroll") for(int _k=0;_k<16;_k++) PIN1(a[_k]); }while(0)

struct P34 { const float* p[34]; float* ws; float* out; };

// ================= K1: serial inference recurrence (the only sequential part) =================
__global__ __launch_bounds__(64, 1) void k1_recur(P34 prm)
{
  const int tid = threadIdx.x;
  const int j   = tid & 15;
  const int grp = tid >> 4;              // 0..3
  const int b   = blockIdx.x*4 + grp;    // chain id (512 blocks)
  const bool act = (j < HID);
  const int  jl  = act ? j : 0;

  const float* __restrict__ seq   = prm.p[0];
  const float* __restrict__ noise = prm.p[1];
  float* __restrict__ ws = prm.ws;

  // inference weights (live through the loop) — loaded once, PINNED in VGPRs
  float w_ii0   = bload(prm.p[10],      jl, act);
  float w_ii1   = bload(prm.p[10], 10 + jl, act);
  float b_in_in = bload(prm.p[11], jl, act);
  float w_in_j_e[16], w_in_j_z[16], w_in_h[16], w_in_mu[16], w_in_sg[16];
  loadrot<10,10>(w_in_j_e, prm.p[12],       j, j, act);
  loadrot<10,10>(w_in_j_z, prm.p[12] + 100, j, j, act);
  float b_in_j  = bload(prm.p[13], jl, act);
  loadrot<10,10>(w_in_h,  prm.p[14], j, j, act);  float b_in_h  = bload(prm.p[15], jl, act);
  loadrot<10,10>(w_in_mu, prm.p[16], j, j, act);  float b_in_mu = bload(prm.p[17], jl, act);
  loadrot<10,10>(w_in_sg, prm.p[18], j, j, act);  float b_in_sg = bload(prm.p[19], jl, act);
  PIN16(w_in_j_e); PIN16(w_in_j_z); PIN16(w_in_h); PIN16(w_in_mu); PIN16(w_in_sg);
  PIN1(w_ii0); PIN1(w_ii1); PIN1(b_in_in); PIN1(b_in_j); PIN1(b_in_h);
  PIN1(b_in_mu); PIN1(b_in_sg);

  float rz[16];

  auto ldx = [&](int t){ return *reinterpret_cast<const float2*>(seq + t*BATCH*2 + b*2); };
  auto lde = [&](int t){ return noise[t*BATCH*HID + b*HID + jl]; };

  { // t = 0: first_inference (weights die after this scope) + KL vs N(0,1)
    float w0 = bload(prm.p[2],      jl, act);
    float w1 = bload(prm.p[2], 10 + jl, act);
    float bb = bload(prm.p[3], jl, act);
    float w_h[16], w_mu[16], w_sg[16];
    loadrot<10,10>(w_h,  prm.p[4], j, j, act);  float b_h  = bload(prm.p[5], jl, act);
    loadrot<10,10>(w_mu, prm.p[6], j, j, act);  float b_mu = bload(prm.p[7], jl, act);
    loadrot<10,10>(w_sg, prm.p[8], j, j, act);  float b_sg = bload(prm.p[9], jl, act);
    float2 x = ldx(0);
    float eps = lde(0);
    float h0 = ftanh(fmaf(x.x, w0, fmaf(x.y, w1, bb)));
    float r0[16]; ROT16(r0, h0);
    float h1 = ftanh(dot16(r0, w_h, b_h));
    float r1[16]; ROT16(r1, h1);
    float mu = ftanh(dot16(r1, w_mu, b_mu));
    float sg = fsigm(dot16(r1, w_sg, b_sg)) + 0.001f;
    float term = act ? (sg + mu*mu - __logf(sg)) : 0.f;
    term += xor16<1>(term); term += xor16<2>(term); term += xor16<4>(term); term += xor16<8>(term);
    if (j == 0) ws[KLOFF + b] = 0.5f*term;            // kl_half(t=0)
    float z = fmaf(sg, eps, mu);
    if (act){
      ws[ZOFF   + b*HID + jl] = z;
      ws[QMUOFF + b*HID + jl] = mu;
      ws[QSGOFF + b*HID + jl] = sg;
    }
    ROT16(rz, z);
  }

  // 2-deep prefetch of (x, eps)
  float2 xa = ldx(1);            float ea = lde(1);
  float2 xb = ldx(2 < T_STEPS ? 2 : T_STEPS-1);
  float  eb = lde(2 < T_STEPS ? 2 : T_STEPS-1);

  for (int t = 1; t < T_STEPS; ++t){
    float2 x = xa; float eps = ea;
    xa = xb; ea = eb;
    int tn = (t+2 < T_STEPS) ? t+2 : T_STEPS-1;
    xb = ldx(tn); eb = lde(tn);

    float e = ftanh(fmaf(x.x, w_ii0, fmaf(x.y, w_ii1, b_in_in)));
    float re[16]; ROT16(re, e);
    float hj = ftanh(dot16(re, w_in_j_e, b_in_j) + dot16(rz, w_in_j_z, 0.f));
    float rhj[16]; ROT16(rhj, hj);
    float hi = ftanh(dot16(rhj, w_in_h, b_in_h));
    float rhi[16]; ROT16(rhi, hi);
    float q_mu = ftanh(dot16(rhi, w_in_mu, b_in_mu));
    float q_sg = fsigm(dot16(rhi, w_in_sg, b_in_sg)) + 0.001f;
    float z = fmaf(q_sg, eps, q_mu);
    int zW = (t*BATCH + b)*HID + jl;
    if (act){
      ws[ZOFF   + zW] = z;
      ws[QMUOFF + zW] = q_mu;
      ws[QSGOFF + zW] = q_sg;
    }
    ROT16(rz, z);
  }
}

// ================= K2 bodies (parallel over (t,b)) =================
__device__ __forceinline__ void k2_kl_body(const P34& prm, int blk, int tid)
{
  const int j   = tid & 15;
  const int gg  = blk*16 + (tid >> 4);   // 16384 groups
  const bool act = (j < HID);
  const int  jl  = act ? j : 0;
  float* __restrict__ ws = prm.ws;

  float w_h[16], w_mu[16], w_sg[16];
  loadrot<10,10>(w_h,  prm.p[20], j, j, act);  float b_h  = bload(prm.p[21], jl, act);
  loadrot<10,10>(w_mu, prm.p[22], j, j, act);  float b_mu = bload(prm.p[23], jl, act);
  loadrot<10,10>(w_sg, prm.p[24], j, j, act);  float b_sg = bload(prm.p[25], jl, act);

  for (int it = 0; it < 32; ++it){
    int i = it*16384 + gg;                      // item over t=1..255, b
    if (i >= (T_STEPS-1)*BATCH) break;
    int t = 1 + (i >> 11);
    int b = i & (BATCH-1);
    int zo = ((t-1)*BATCH + b)*HID + jl;
    int qo = (t*BATCH + b)*HID + jl;
    float zp  = act ? ws[ZOFF   + zo] : 0.f;
    float qmu = act ? ws[QMUOFF + qo] : 0.f;
    float qsg = act ? ws[QSGOFF + qo] : 1.f;
    float rzp[16]; ROT16(rzp, zp);
    float th = ftanh(dot16(rzp, w_h, b_h));
    float rth[16]; ROT16(rth, th);
    float prmu = ftanh(dot16(rth, w_mu, b_mu));
    float prsg = ftanh(dot16(rth, w_sg, b_sg));
    float term = 0.f;
    if (act){
      float dmu = prmu - qmu;
      float rp  = frcp(prsg);
      term = __logf(prsg*frcp(qsg)) + (qsg + dmu*dmu)*rp;
    }
    term += xor16<1>(term); term += xor16<2>(term); term += xor16<4>(term); term += xor16<8>(term);
    if (j == 0) ws[KLOFF + t*BATCH + b] = 0.5f*term;
  }
}

__device__ __forceinline__ void k2_gen_body(const P34& prm, int blk, int tid)
{
  const int j   = tid & 15;
  const int gg  = blk*16 + (tid >> 4);
  const bool act = (j < HID);
  const int  jl  = act ? j : 0;
  float* __restrict__ ws = prm.ws;
  const float* __restrict__ seq = prm.p[0];
  float* __restrict__ out = prm.out;

  float w_g1[16], w_g2[16], w_go_mu[16], w_go_sg[16];
  loadrot<10,10>(w_g1, prm.p[26], j, j, act);  float b_g1 = bload(prm.p[27], jl, act);
  loadrot<10,10>(w_g2, prm.p[28], j, j, act);  float b_g2 = bload(prm.p[29], jl, act);
  const bool isd = (j < 2);
  loadrot<10,2>(w_go_mu, prm.p[30], j, j, isd);  float b_go_mu = bload(prm.p[31], j, isd);
  loadrot<10,2>(w_go_sg, prm.p[32], j, j, isd);  float b_go_sg = bload(prm.p[33], j, isd);

  for (int it = 0; it < 32; ++it){
    int i = it*16384 + gg;                      // exactly 524288 items
    int t = i >> 11;
    int b = i & (BATCH-1);
    int zo = (t*BATCH + b)*HID + jl;
    float zc = act ? ws[ZOFF + zo] : 0.f;
    float rz[16]; ROT16(rz, zc);
    float g1 = fmaxf(dot16(rz, w_g1, b_g1), 0.f);
    float r1[16]; ROT16(r1, g1);
    float g2 = fmaxf(dot16(r1, w_g2, b_g2), 0.f);
    float r2[16]; ROT16(r2, g2);
    float m = fsigm(dot16(r2, w_go_mu, b_go_mu));
    float s = fsigm(dot16(r2, w_go_sg, b_go_sg));
    float ll = 0.f;
    int go = (t*BATCH + b)*2;
    if (isd){
      float xd = seq[go + j];
      out[go + j] = m;
      float dd = xd - m;
      ll = __logf(s) + dd*dd*frcp(s);
    }
    ll += xor16<1>(ll);
    if (j == 0) ws[LLOFF + t*BATCH + b] = -0.5f*ll;
  }
}

__global__ __launch_bounds__(256, 1) void k2_fused(P34 prm)
{
  if (blockIdx.x < 1024) k2_gen_body(prm, blockIdx.x, threadIdx.x);
  else                   k2_kl_body(prm, blockIdx.x - 1024, threadIdx.x);
}

// ================= K3: loss reduction over t (parallel over t-quarters too) =================
__global__ __launch_bounds__(256, 1) void k3_loss(P34 prm)
{
  __shared__ float red[256];
  const int tid = threadIdx.x;
  const int bl  = tid & 63;
  const int q   = tid >> 6;                      // t-quarter
  const int b   = blockIdx.x*64 + bl;            // grid 32 -> 2048
  const float* __restrict__ kl = prm.ws + KLOFF;
  const float* __restrict__ ll = prm.ws + LLOFF;
  float s = 0.f;
  #pragma unroll 4
  for (int tt = 0; tt < 64; ++tt){
    int t = q*64 + tt;
    s += kl[t*BATCH + b] + ll[t*BATCH + b];
  }
  red[tid] = s;
  __syncthreads();
  if (q == 0){
    s = red[bl] + red[bl+64] + red[bl+128] + red[bl+192];
    const float LOGPI = 1.1447298858494002f;
    prm.out[T_STEPS*BATCH*2 + b] = -s*(1.0f/(float)T_STEPS) + 5.0f + LOGPI;
  }
}

extern "C" void kernel_launch(void* const* d_in, const int* in_sizes, int n_in,
                              void* d_out, int out_size, void* d_ws, size_t ws_size,
                              hipStream_t stream) {
  P34 prm;
  for (int i = 0; i < 34; ++i) prm.p[i] = (const float*)d_in[i];
  prm.ws  = (float*)d_ws;      // needs 64 MiB
  prm.out = (float*)d_out;
  hipLaunchKernelGGL(k1_recur, dim3(512),  dim3(64),  0, stream, prm);
  hipLaunchKernelGGL(k2_fused, dim3(2048), dim3(256), 0, stream, prm);
  hipLaunchKernelGGL(k3_loss,  dim3(32),   dim3(256), 0, stream, prm);
}